// Round 1
// baseline (317.070 us; speedup 1.0000x reference)
//
#include <hip/hip_runtime.h>
#include <math.h>

#define BB   64
#define PP   32
#define RR   4096
#define NATT 7
#define NLAB 32
#define NCH  (PP * NATT)   // 224

// ws accumulator layout (floats): [0]=l_xy [1]=l_wl [2]=l_rot [3]=l_obj [4]=l_noobj

__device__ __forceinline__ float sigmoidf_(float x) {
    return 1.0f / (1.0f + expf(-x));
}

// Sum -safe_log(1 - sigmoid(conf)) over ALL B*P*R cells (obj cells corrected later).
__global__ __launch_bounds__(256) void noobj_kernel(const float* __restrict__ preds,
                                                    float* __restrict__ acc) {
    const float4* p4 = reinterpret_cast<const float4*>(preds);
    const int total4 = BB * PP * RR / 4;  // 2,097,152 float4s
    float local = 0.0f;
    for (int f = blockIdx.x * blockDim.x + threadIdx.x; f < total4;
         f += gridDim.x * blockDim.x) {
        int row = f >> 10;            // R/4 = 1024 float4 per (b,pp) row
        int b   = row >> 5;
        int pp  = row & 31;
        int a4  = ((b * NCH + pp * NATT + 6) << 10) + (f & 1023);
        float4 v = p4[a4];
        float xs[4] = {v.x, v.y, v.z, v.w};
#pragma unroll
        for (int u = 0; u < 4; ++u) {
            float conf = sigmoidf_(xs[u]);
            float l    = fmaxf(logf(1.0f - conf), -100.0f);
            local -= l;
        }
    }
    // wave (64-lane) reduce
#pragma unroll
    for (int off = 32; off > 0; off >>= 1) local += __shfl_down(local, off);
    __shared__ float s[4];
    int lane = threadIdx.x & 63, w = threadIdx.x >> 6;
    if (lane == 0) s[w] = local;
    __syncthreads();
    if (threadIdx.x == 0) {
        atomicAdd(&acc[4], s[0] + s[1] + s[2] + s[3]);
    }
}

// One thread per (image, label). Last-write-wins dedup, then gather the 7
// pred attrs at the cell and accumulate all obj-cell loss terms.
__global__ __launch_bounds__(256) void label_kernel(const float* __restrict__ preds,
                                                    const float* __restrict__ labels,
                                                    float* __restrict__ acc) {
    int idx = blockIdx.x * blockDim.x + threadIdx.x;
    if (idx >= BB * NLAB) return;
    int b = idx >> 5;
    int k = idx & 31;
    const float* lab = labels + (size_t)(b * NLAB + k) * NATT;

    float ang = lab[0] + 204.8f;          // R*CELL_ANGLE/2 in fp32
    float af  = ang / 0.1f;
    int i = (int)floorf(af);
    i = min(max(i, 0), RR - 1);
    float dep = lab[1];                   // /CELL_DEPTH == /1.0
    int j = (int)floorf(dep);
    j = min(max(j, 0), PP - 1);

    // numpy scatter semantics: later label with same (i,j) overwrites this one.
    for (int kk = k + 1; kk < NLAB; ++kk) {
        const float* l2 = labels + (size_t)(b * NLAB + kk) * NATT;
        float a2 = (l2[0] + 204.8f) / 0.1f;
        int i2 = min(max((int)floorf(a2), 0), RR - 1);
        int j2 = min(max((int)floorf(l2[1]), 0), PP - 1);
        if (i2 == i && j2 == j) return;
    }

    float fx = af  - (float)i;
    float fy = dep - (float)j;

    const float* pb = preds + ((size_t)b * NCH + (size_t)j * NATT) * RR + i;
    float p0 = pb[0 * RR], p1 = pb[1 * RR], p2 = pb[2 * RR], p3 = pb[3 * RR];
    float p4 = pb[4 * RR], p5 = pb[5 * RR], p6 = pb[6 * RR];

    float s0 = sigmoidf_(p0), s1 = sigmoidf_(p1);
    float l_xy = (s0 - fx) * (s0 - fx) + (s1 - fy) * (s1 - fy);

    float tw = logf(lab[2] / 1.6f + 1e-16f);
    float tl = logf(lab[3] / 3.9f + 1e-16f);
    float l_wl = (p2 - tw) * (p2 - tw) + (p3 - tl) * (p3 - tl);

    float r0 = tanhf(p4), r1 = tanhf(p5);
    float l_rot = (r0 - lab[4]) * (r0 - lab[4]) + (r1 - lab[5]) * (r1 - lab[5]);

    float conf  = sigmoidf_(p6);
    float l_obj = -fmaxf(logf(conf), -100.0f);
    // this cell was counted in the all-cells noobj sum; remove it
    float noobj_part = -fmaxf(logf(1.0f - conf), -100.0f);

    atomicAdd(&acc[0], l_xy);
    atomicAdd(&acc[1], l_wl);
    atomicAdd(&acc[2], l_rot);
    atomicAdd(&acc[3], l_obj);
    atomicAdd(&acc[4], -noobj_part);
}

__global__ void finalize_kernel(const float* __restrict__ acc, float* __restrict__ out) {
    if (threadIdx.x == 0 && blockIdx.x == 0) {
        float xy = acc[0], wl = acc[1], rot = acc[2], obj = acc[3], noobj = acc[4];
        out[0] = 10.0f * xy + 10.0f * wl + 20.0f * rot + 20.0f * obj + 1.0f * noobj;
        out[1] = xy;
        out[2] = wl;
        out[3] = rot;
        out[4] = obj;
        out[5] = noobj;
    }
}

extern "C" void kernel_launch(void* const* d_in, const int* in_sizes, int n_in,
                              void* d_out, int out_size, void* d_ws, size_t ws_size,
                              hipStream_t stream) {
    const float* preds  = (const float*)d_in[0];
    const float* labels = (const float*)d_in[1];
    float* out = (float*)d_out;
    float* acc = (float*)d_ws;

    hipMemsetAsync(acc, 0, 8 * sizeof(float), stream);

    label_kernel<<<(BB * NLAB + 255) / 256, 256, 0, stream>>>(preds, labels, acc);
    noobj_kernel<<<2048, 256, 0, stream>>>(preds, acc);
    finalize_kernel<<<1, 64, 0, stream>>>(acc, out);
}

// Round 2
// 286.963 us; speedup vs baseline: 1.1049x; 1.1049x over previous
//
#include <hip/hip_runtime.h>
#include <math.h>

#define BB    64
#define PP    32
#define RR    4096
#define NATT  7
#define NLAB  32
#define NCH   (PP * NATT)       // 224
#define GRID1 2048
#define BLK1  256
#define TOT4  (BB * PP * RR / 4) // 2,097,152 float4s of conf channel space

// d_ws layout: partials[GRID1][5] floats — every block writes its own slot,
// so no zero-init of d_ws is needed (harness poisons it with 0xAA).

__device__ __forceinline__ float sigmoidf_(float x) {
    return 1.0f / (1.0f + expf(-x));
}

__global__ __launch_bounds__(BLK1) void fused_kernel(const float* __restrict__ preds,
                                                     const float* __restrict__ labels,
                                                     float* __restrict__ partials) {
    const int gid = blockIdx.x * BLK1 + threadIdx.x;
    float l_xy = 0.0f, l_wl = 0.0f, l_rot = 0.0f, l_obj = 0.0f, l_noobj = 0.0f;

    // ---- all-cells noobj sum over the conf channel (attr 6 of each depth) ----
    const float4* p4 = reinterpret_cast<const float4*>(preds);
    for (int f = gid; f < TOT4; f += GRID1 * BLK1) {
        int row = f >> 10;            // 1024 float4 per (b,pp) row of R=4096
        int b   = row >> 5;
        int pp  = row & 31;
        int a4  = ((b * NCH + pp * NATT + 6) << 10) + (f & 1023);
        float4 v = p4[a4];
        float xs[4] = {v.x, v.y, v.z, v.w};
#pragma unroll
        for (int u = 0; u < 4; ++u) {
            float conf = sigmoidf_(xs[u]);
            l_noobj -= fmaxf(logf(1.0f - conf), -100.0f);
        }
    }

    // ---- per-label obj-cell terms (first B*NLAB = 2048 threads) ----
    if (gid < BB * NLAB) {
        int b = gid >> 5;
        int k = gid & 31;
        const float* lab = labels + (size_t)(b * NLAB + k) * NATT;

        float af = (lab[0] + 204.8f) / 0.1f;     // angle -> fractional bin
        int i = min(max((int)floorf(af), 0), RR - 1);
        float dep = lab[1];
        int j = min(max((int)floorf(dep), 0), PP - 1);

        // numpy scatter: last write wins — skip if a later label hits same cell
        bool overwritten = false;
        for (int kk = k + 1; kk < NLAB; ++kk) {
            const float* l2 = labels + (size_t)(b * NLAB + kk) * NATT;
            float a2 = (l2[0] + 204.8f) / 0.1f;
            int i2 = min(max((int)floorf(a2), 0), RR - 1);
            int j2 = min(max((int)floorf(l2[1]), 0), PP - 1);
            if (i2 == i && j2 == j) { overwritten = true; break; }
        }

        if (!overwritten) {
            float fx = af  - (float)i;
            float fy = dep - (float)j;

            const float* pb = preds + ((size_t)b * NCH + (size_t)j * NATT) * RR + i;
            float p0 = pb[0 * RR], p1 = pb[1 * RR], p2 = pb[2 * RR], p3 = pb[3 * RR];
            float q0 = pb[4 * RR], q1 = pb[5 * RR], p6 = pb[6 * RR];

            float s0 = sigmoidf_(p0), s1 = sigmoidf_(p1);
            l_xy = (s0 - fx) * (s0 - fx) + (s1 - fy) * (s1 - fy);

            float tw = logf(lab[2] / 1.6f + 1e-16f);
            float tl = logf(lab[3] / 3.9f + 1e-16f);
            l_wl = (p2 - tw) * (p2 - tw) + (p3 - tl) * (p3 - tl);

            float r0 = tanhf(q0), r1 = tanhf(q1);
            l_rot = (r0 - lab[4]) * (r0 - lab[4]) + (r1 - lab[5]) * (r1 - lab[5]);

            float conf = sigmoidf_(p6);
            l_obj = -fmaxf(logf(conf), -100.0f);
            // this cell was included in the all-cells noobj sum; remove it
            l_noobj += fmaxf(logf(1.0f - conf), -100.0f);
        }
    }

    // ---- block reduction of 5 components ----
    float v0 = l_xy, v1 = l_wl, v2 = l_rot, v3 = l_obj, v4 = l_noobj;
#pragma unroll
    for (int off = 32; off > 0; off >>= 1) {
        v0 += __shfl_down(v0, off);
        v1 += __shfl_down(v1, off);
        v2 += __shfl_down(v2, off);
        v3 += __shfl_down(v3, off);
        v4 += __shfl_down(v4, off);
    }
    __shared__ float s[4][5];
    int lane = threadIdx.x & 63, w = threadIdx.x >> 6;
    if (lane == 0) {
        s[w][0] = v0; s[w][1] = v1; s[w][2] = v2; s[w][3] = v3; s[w][4] = v4;
    }
    __syncthreads();
    if (threadIdx.x == 0) {
        float* dst = partials + (size_t)blockIdx.x * 5;
#pragma unroll
        for (int c = 0; c < 5; ++c)
            dst[c] = s[0][c] + s[1][c] + s[2][c] + s[3][c];
    }
}

// 320 threads = 5 waves; wave w reduces component w over GRID1 block slots.
__global__ __launch_bounds__(320) void reduce_kernel(const float* __restrict__ partials,
                                                     float* __restrict__ out) {
    int w    = threadIdx.x >> 6;   // component 0..4
    int lane = threadIdx.x & 63;
    float sum = 0.0f;
    for (int b = lane; b < GRID1; b += 64) sum += partials[(size_t)b * 5 + w];
#pragma unroll
    for (int off = 32; off > 0; off >>= 1) sum += __shfl_down(sum, off);
    __shared__ float comp[5];
    if (lane == 0) comp[w] = sum;
    __syncthreads();
    if (threadIdx.x == 0) {
        float xy = comp[0], wl = comp[1], rot = comp[2], obj = comp[3], noobj = comp[4];
        out[0] = 10.0f * xy + 10.0f * wl + 20.0f * rot + 20.0f * obj + noobj;
        out[1] = xy;
        out[2] = wl;
        out[3] = rot;
        out[4] = obj;
        out[5] = noobj;
    }
}

extern "C" void kernel_launch(void* const* d_in, const int* in_sizes, int n_in,
                              void* d_out, int out_size, void* d_ws, size_t ws_size,
                              hipStream_t stream) {
    const float* preds  = (const float*)d_in[0];
    const float* labels = (const float*)d_in[1];
    float* out      = (float*)d_out;
    float* partials = (float*)d_ws;

    fused_kernel<<<GRID1, BLK1, 0, stream>>>(preds, labels, partials);
    reduce_kernel<<<1, 320, 0, stream>>>(partials, out);
}